// Round 7
// baseline (436.813 us; speedup 1.0000x reference)
//
#include <hip/hip_runtime.h>

typedef unsigned short u16;
typedef u16 u16x2 __attribute__((ext_vector_type(2)));
typedef u16 u16x4 __attribute__((ext_vector_type(4)));
typedef u16 u16x8 __attribute__((ext_vector_type(8)));
typedef __bf16 bf16x8 __attribute__((ext_vector_type(8)));
typedef float f32x4 __attribute__((ext_vector_type(4)));
typedef float f32x2 __attribute__((ext_vector_type(2)));

#define MFMA16(A, B, C) __builtin_amdgcn_mfma_f32_16x16x32_bf16(A, B, C, 0, 0, 0)

// Constants: B=2, S=2048, E=512, H=8, HD=64
#define SB 2
#define SS 2048
#define SE 512
#define SH 8
#define SHD 64

// Hardware RNE f32->bf16 (v_cvt_pk_bf16_f32 via compiler; same rounding as
// the old manual add-0x7FFF sequence -> bit-identical tensors).
__device__ __forceinline__ u16 f2b(float f) {
  return __builtin_bit_cast(u16, (__bf16)f);
}

__device__ __forceinline__ bf16x8 as_bf16x8(u16x8 v) {
  return __builtin_bit_cast(bf16x8, v);
}

// ---------------------------------------------------------------------------
// Merged prep: blocks [0,2048) convert X f32->bf16; blocks [2048,2816)
// transpose+convert Wqkv into WqkvT [1536,512] bf16.
// ---------------------------------------------------------------------------
__global__ __launch_bounds__(256)
void prep_kernel(const float* __restrict__ X, u16* __restrict__ Xb,
                 const float* __restrict__ Wqkv, u16* __restrict__ WqkvT)
{
  __shared__ float t[32][33];
  const int tid = threadIdx.x;
  if (blockIdx.x < 2048) {
    const int i = (blockIdx.x * 256 + tid) * 4;
    const float4 v = *(const float4*)&X[i];
    u16x4 o;
    o[0] = f2b(v.x); o[1] = f2b(v.y); o[2] = f2b(v.z); o[3] = f2b(v.w);
    *(u16x4*)&Xb[i] = o;
  } else {
    const int bx = blockIdx.x - 2048;          // 768 blocks: 48 n x 16 k
    const int n0 = (bx % 48) * 32, k0 = (bx / 48) * 32;
    const int r = tid >> 3, c4 = (tid & 7) * 4;
    const float4 v = *(const float4*)&Wqkv[(size_t)(k0 + r) * 1536 + n0 + c4];
    t[r][c4 + 0] = v.x; t[r][c4 + 1] = v.y; t[r][c4 + 2] = v.z; t[r][c4 + 3] = v.w;
    __syncthreads();
    u16x4 o;
    o[0] = f2b(t[c4 + 0][r]);
    o[1] = f2b(t[c4 + 1][r]);
    o[2] = f2b(t[c4 + 2][r]);
    o[3] = f2b(t[c4 + 3][r]);
    *(u16x4*)&WqkvT[(n0 + r) * 512 + k0 + c4] = o;
  }
}

// ---------------------------------------------------------------------------
// Standalone W transpose (used post-attn for WoT).
// ---------------------------------------------------------------------------
__global__ __launch_bounds__(256)
void wtrans_kernel(const float* __restrict__ in, u16* __restrict__ out, int N)
{
  __shared__ float t[32][33];
  const int tid = threadIdx.x;
  const int r = tid >> 3, c4 = (tid & 7) * 4;
  const int k0 = blockIdx.y * 32, n0 = blockIdx.x * 32;
  const float4 v = *(const float4*)&in[(size_t)(k0 + r) * N + n0 + c4];
  t[r][c4 + 0] = v.x; t[r][c4 + 1] = v.y; t[r][c4 + 2] = v.z; t[r][c4 + 3] = v.w;
  __syncthreads();
  u16x4 o;
  o[0] = f2b(t[c4 + 0][r]);
  o[1] = f2b(t[c4 + 1][r]);
  o[2] = f2b(t[c4 + 2][r]);
  o[3] = f2b(t[c4 + 3][r]);
  *(u16x4*)&out[(n0 + r) * 512 + k0 + c4] = o;
}

// ---------------------------------------------------------------------------
// Unified bf16 GEMM (UNCHANGED — control).
// ---------------------------------------------------------------------------
template <int MODE>
__global__ __launch_bounds__(256, 2)
void gemm_kernel(const u16* __restrict__ A, const u16* __restrict__ Bt,
                 const float* __restrict__ bias,
                 u16* __restrict__ Q, u16* __restrict__ K, u16* __restrict__ Vt,
                 float* __restrict__ Out)
{
  __shared__ __align__(16) u16 As[128 * 40];
  __shared__ __align__(16) u16 Bs[128 * 40];
  const int tid  = threadIdx.x;
  const int lane = tid & 63, wave = tid >> 6, quad = lane >> 4, l16 = lane & 15;
  const int m0 = blockIdx.y * 128, n0 = blockIdx.x * 128;
  const int wr = (wave >> 1) * 64, wc = (wave & 1) * 64;
  const int sr = tid >> 2, sc = (tid & 3) * 8;

  const f32x4 z4 = {0.f, 0.f, 0.f, 0.f};
  f32x4 acc[4][4];
#pragma unroll
  for (int i = 0; i < 4; i++)
#pragma unroll
    for (int j = 0; j < 4; j++) acc[i][j] = z4;

  for (int k0 = 0; k0 < 512; k0 += 32) {
    const u16x8 a0 = *(const u16x8*)&A[(m0 + sr) * 512 + k0 + sc];
    const u16x8 a1 = *(const u16x8*)&A[(m0 + 64 + sr) * 512 + k0 + sc];
    const u16x8 b0 = *(const u16x8*)&Bt[(n0 + sr) * 512 + k0 + sc];
    const u16x8 b1 = *(const u16x8*)&Bt[(n0 + 64 + sr) * 512 + k0 + sc];
    __syncthreads();
    *(u16x8*)&As[sr * 40 + sc]        = a0;
    *(u16x8*)&As[(64 + sr) * 40 + sc] = a1;
    *(u16x8*)&Bs[sr * 40 + sc]        = b0;
    *(u16x8*)&Bs[(64 + sr) * 40 + sc] = b1;
    __syncthreads();
    bf16x8 af[4], bf[4];
#pragma unroll
    for (int i = 0; i < 4; i++) {
      af[i] = as_bf16x8(*(const u16x8*)&As[(wr + i * 16 + l16) * 40 + quad * 8]);
      bf[i] = as_bf16x8(*(const u16x8*)&Bs[(wc + i * 16 + l16) * 40 + quad * 8]);
    }
#pragma unroll
    for (int i = 0; i < 4; i++)
#pragma unroll
      for (int j = 0; j < 4; j++) acc[i][j] = MFMA16(af[i], bf[j], acc[i][j]);
  }

#pragma unroll
  for (int tm = 0; tm < 4; tm++) {
#pragma unroll
    for (int tn = 0; tn < 4; tn++) {
#pragma unroll
      for (int r = 0; r < 4; r++) {
        const int gm = m0 + wr + tm * 16 + quad * 4 + r;
        const int gn = n0 + wc + tn * 16 + l16;
        const float v = acc[tm][tn][r] + bias[gn];
        if (MODE == 0) {
          const int bb = gm >> 11, s = gm & 2047;
          const int hh = gn / 192, j = gn - hh * 192;
          const int bh = bb * SH + hh;
          if (j < 64)
            Q[(bh * SS + s) * SHD + j] = f2b(v * 0.125f);
          else if (j < 128)
            K[(bh * SS + s) * SHD + (j - 64)] = f2b(v);
          else
            Vt[(bh * SHD + (j - 128)) * SS + s] = f2b(v);
        } else {
          Out[gm * 512 + gn] = v;
        }
      }
    }
  }
}

// ---------------------------------------------------------------------------
// Fused attention v6 (swapped-operand): 2048 blocks x 8 waves; block = 16
// q-rows, wave w = keys [w*256, w*256+256), single K pass.
// QK^T computed as mfma(K, Q) -> lane holds P[q=l16][key = ct*16+quad*4+r]:
// 4 CONSECUTIVE keys of ONE q-row per f32x4 reg. This vectorizes every
// epilogue phase (vs v5's 64 scalar ops each):
//   - softmax reduce: in-lane tree + 2 shuffles (xor 16/32)
//   - bf16 P -> LDS : 16 ds_write_b64
//   - fp32 P -> HBM : 16 nontemporal f32x4 stores (issued LAST)
//   - PV swapped (mfma(V, P)) -> O partials: 4 ds_write_b128
// Loads are IDENTICAL to v5 (A/B frag layouts coincide); MFMA accumulation
// order unchanged -> scores and O bit-identical; only softmax-sum
// association order changes.
// ---------------------------------------------------------------------------
#define PSTR 264
#define PWAVE (16 * PSTR)   // u16 elems per wave region (8448 B)
#define OSTR 72             // f32 stride for O-partial staging (16B aligned)

__global__ __launch_bounds__(512, 4)
void attn_kernel(const u16* __restrict__ Q, const u16* __restrict__ K,
                 const u16* __restrict__ Vt, u16* __restrict__ values,
                 float* __restrict__ attn)
{
  __shared__ __align__(16) u16 p_lds[8 * PWAVE];  // 67,584 B
  __shared__ float srm[8][16];
  __shared__ float srl[8][16];

  const int tid  = threadIdx.x;
  const int lane = tid & 63, wave = tid >> 6, quad = lane >> 4, l16 = lane & 15;
  const int q0 = blockIdx.x * 16;
  const int h = blockIdx.y, b = blockIdx.z, bh = b * SH + h;

  const u16* Qb = Q + (size_t)bh * SS * SHD;
  const u16* Kb = K + (size_t)bh * SS * SHD;
  const u16* Vb = Vt + (size_t)bh * SHD * SS;

  // Q fragments (B-operand now; same layout/loads as before)
  const bf16x8 aq0 = as_bf16x8(*(const u16x8*)&Qb[(q0 + l16) * SHD + quad * 8]);
  const bf16x8 aq1 = as_bf16x8(*(const u16x8*)&Qb[(q0 + l16) * SHD + 32 + quad * 8]);

  // ---- scores: acc[ct][r] = S[q = l16][key = ct*16 + quad*4 + r] ----
  f32x4 acc[16];
#pragma unroll
  for (int ct = 0; ct < 16; ct++) {
    const int kb = wave * 256 + ct * 16;
    bf16x8 bk0 = as_bf16x8(*(const u16x8*)&Kb[(kb + l16) * SHD + quad * 8]);
    bf16x8 bk1 = as_bf16x8(*(const u16x8*)&Kb[(kb + l16) * SHD + 32 + quad * 8]);
    f32x4 c = {0.f, 0.f, 0.f, 0.f};
    c = MFMA16(bk0, aq0, c);   // SWAPPED: A=K, B=Q
    c = MFMA16(bk1, aq1, c);
    acc[ct] = c;
  }

  // ---- per-lane stats for row q=l16 (64 in-reg values) ----
  f32x4 mx4 = acc[0];
#pragma unroll
  for (int ct = 1; ct < 16; ct++)
#pragma unroll
    for (int r = 0; r < 4; r++) mx4[r] = fmaxf(mx4[r], acc[ct][r]);
  float m = fmaxf(fmaxf(mx4[0], mx4[1]), fmaxf(mx4[2], mx4[3]));
  m = fmaxf(m, __shfl_xor(m, 16));
  m = fmaxf(m, __shfl_xor(m, 32));

  f32x4 s4 = {0.f, 0.f, 0.f, 0.f};
#pragma unroll
  for (int ct = 0; ct < 16; ct++)
#pragma unroll
    for (int r = 0; r < 4; r++) {
      const float p = __expf(acc[ct][r] - m);
      acc[ct][r] = p;
      s4[r] += p;
    }
  float s = (s4[0] + s4[1]) + (s4[2] + s4[3]);
  s += __shfl_xor(s, 16);
  s += __shfl_xor(s, 32);

  if (lane < 16) {   // quad == 0
    srm[wave][l16] = m;
    srl[wave][l16] = s;
  }
  __syncthreads();  // barrier #1

  // ---- global merge: scale = exp(m_w - m_g) / l_g ----
  float mg = srm[0][l16];
#pragma unroll
  for (int w = 1; w < 8; w++) mg = fmaxf(mg, srm[w][l16]);
  float lg = 0.f;
#pragma unroll
  for (int w = 0; w < 8; w++) lg += srl[w][l16] * __expf(srm[w][l16] - mg);
  const float scale = __expf(m - mg) / lg;
#pragma unroll
  for (int ct = 0; ct < 16; ct++)
#pragma unroll
    for (int r = 0; r < 4; r++) acc[ct][r] *= scale;

  // ---- bf16 P -> wave-private LDS ([q][key], 16x ds_write_b64) ----
  u16* pl = &p_lds[wave * PWAVE];
#pragma unroll
  for (int ct = 0; ct < 16; ct++) {
    u16x4 t;
#pragma unroll
    for (int r = 0; r < 4; r++) t[r] = f2b(acc[ct][r]);
    *(u16x4*)&pl[l16 * PSTR + ct * 16 + quad * 4] = t;
  }

  // ---- PV (swapped: A=V, B=P) with 2-deep V prefetch ----
  f32x4 oacc[4];
#pragma unroll
  for (int nt = 0; nt < 4; nt++) oacc[nt] = (f32x4){0.f, 0.f, 0.f, 0.f};
  bf16x8 vbuf[2][4];
  {
    const int sb = wave * 256 + quad * 8;
#pragma unroll
    for (int nt = 0; nt < 4; nt++)
      vbuf[0][nt] = as_bf16x8(*(const u16x8*)&Vb[(nt * 16 + l16) * SS + sb]);
  }
#pragma unroll
  for (int kc = 0; kc < 8; kc++) {
    if (kc < 7) {
      const int sb = wave * 256 + (kc + 1) * 32 + quad * 8;
#pragma unroll
      for (int nt = 0; nt < 4; nt++)
        vbuf[(kc + 1) & 1][nt] =
            as_bf16x8(*(const u16x8*)&Vb[(nt * 16 + l16) * SS + sb]);
    }
    bf16x8 pa = as_bf16x8(*(const u16x8*)&pl[l16 * PSTR + kc * 32 + quad * 8]);
#pragma unroll
    for (int nt = 0; nt < 4; nt++)
      oacc[nt] = MFMA16(vbuf[kc & 1][nt], pa, oacc[nt]);  // O[q=l16][d]
  }

  // ---- O partials [q][d] into own LDS region (4x ds_write_b128) ----
  float* op = (float*)pl;  // 16*OSTR*4 = 4608 B of 8448 B region
#pragma unroll
  for (int nt = 0; nt < 4; nt++)
    *(f32x4*)&op[l16 * OSTR + nt * 16 + quad * 4] = oacc[nt];
  __syncthreads();  // barrier #2

  // ---- cross-wave reduce + values write ----
  const int q = tid >> 5, d0 = (tid & 31) * 2;
  f32x2 s2 = {0.f, 0.f};
#pragma unroll
  for (int w = 0; w < 8; w++) {
    const float* opw = (const float*)&p_lds[w * PWAVE];
    s2 += *(const f32x2*)&opw[q * OSTR + d0];
  }
  u16x2 o2;
  o2[0] = f2b(s2[0]);
  o2[1] = f2b(s2[1]);
  *(u16x2*)&values[((size_t)(b * SS + q0 + q) * SH + h) * SHD + d0] = o2;

  // ---- LAST: NT fp32 P stores, 16x f32x4 (fire-and-forget) ----
  float* attn_b = attn + ((size_t)bh * SS + q0) * SS;
#pragma unroll
  for (int ct = 0; ct < 16; ct++) {
    __builtin_nontemporal_store(
        acc[ct],
        (f32x4*)&attn_b[l16 * SS + wave * 256 + ct * 16 + quad * 4]);
  }
}

// ---------------------------------------------------------------------------
// Workspace budget: EXACTLY 16 MiB (verified footprint).
//   ws: Q(4MB) K(4MB) Vt(4MB) values(4MB; Xb aliases it)
//   WqkvT: staged in d_out's attn region (dead until attn_kernel overwrites).
//   WoT:   aliases Q region; produced AFTER attn (Q dead), read by oproj.
// ---------------------------------------------------------------------------
extern "C" void kernel_launch(void* const* d_in, const int* in_sizes, int n_in,
                              void* d_out, int out_size, void* d_ws, size_t ws_size,
                              hipStream_t stream) {
  const float* X    = (const float*)d_in[0];
  const float* Wqkv = (const float*)d_in[1];
  const float* bqkv = (const float*)d_in[2];
  const float* Wo   = (const float*)d_in[3];
  const float* bo   = (const float*)d_in[4];

  float* o_out    = (float*)d_out;                       // [2,2048,512]
  float* attn_out = o_out + SB * SS * SE;                // [2,8,2048,2048]

  const size_t QKV_ELEMS = (size_t)SB * SH * SS * SHD;   // 2,097,152 per tensor
  u16* Q      = (u16*)d_ws;
  u16* K      = Q + QKV_ELEMS;
  u16* Vt     = K + QKV_ELEMS;
  u16* values = Vt + QKV_ELEMS;
  u16* Xb     = values;               // dead before attn writes values
  u16* WqkvT  = (u16*)attn_out;       // dead until attn writes attn_out
  u16* WoT    = Q;                    // Q dead after attn; WoT made post-attn

  // Merged prep: X conversion + Wqkv transpose (one launch)
  prep_kernel<<<dim3(2816), 256, 0, stream>>>(X, Xb, Wqkv, WqkvT);

  // QKV projection: M=4096 (32 m-blocks), N=1536 (12 n-blocks)
  gemm_kernel<0><<<dim3(12, 32), 256, 0, stream>>>(Xb, WqkvT, bqkv, Q, K, Vt, nullptr);
  // Attention: 128 q-tiles x 8 heads x 2 batches, 8 waves each
  attn_kernel<<<dim3(128, 8, 2), 512, 0, stream>>>(Q, K, Vt, values, attn_out);
  // Wo transpose into (now-dead) Q region, then O projection
  wtrans_kernel<<<dim3(16, 16), 256, 0, stream>>>(Wo, WoT, 512);
  gemm_kernel<1><<<dim3(4, 32), 256, 0, stream>>>(values, WoT, bo,
                                                  nullptr, nullptr, nullptr, o_out);
}

// Round 8
// 432.283 us; speedup vs baseline: 1.0105x; 1.0105x over previous
//
#include <hip/hip_runtime.h>

typedef unsigned short u16;
typedef u16 u16x2 __attribute__((ext_vector_type(2)));
typedef u16 u16x4 __attribute__((ext_vector_type(4)));
typedef u16 u16x8 __attribute__((ext_vector_type(8)));
typedef __bf16 bf16x8 __attribute__((ext_vector_type(8)));
typedef float f32x4 __attribute__((ext_vector_type(4)));
typedef float f32x2 __attribute__((ext_vector_type(2)));

#define MFMA16(A, B, C) __builtin_amdgcn_mfma_f32_16x16x32_bf16(A, B, C, 0, 0, 0)

// Constants: B=2, S=2048, E=512, H=8, HD=64
#define SB 2
#define SS 2048
#define SE 512
#define SH 8
#define SHD 64

// Hardware RNE f32->bf16.
__device__ __forceinline__ u16 f2b(float f) {
  return __builtin_bit_cast(u16, (__bf16)f);
}

__device__ __forceinline__ bf16x8 as_bf16x8(u16x8 v) {
  return __builtin_bit_cast(bf16x8, v);
}

// ---------------------------------------------------------------------------
// Merged prep: blocks [0,2048) convert X f32->bf16; blocks [2048,2816)
// transpose+convert Wqkv into WqkvT [1536,512] bf16.
// ---------------------------------------------------------------------------
__global__ __launch_bounds__(256)
void prep_kernel(const float* __restrict__ X, u16* __restrict__ Xb,
                 const float* __restrict__ Wqkv, u16* __restrict__ WqkvT)
{
  __shared__ float t[32][33];
  const int tid = threadIdx.x;
  if (blockIdx.x < 2048) {
    const int i = (blockIdx.x * 256 + tid) * 4;
    const float4 v = *(const float4*)&X[i];
    u16x4 o;
    o[0] = f2b(v.x); o[1] = f2b(v.y); o[2] = f2b(v.z); o[3] = f2b(v.w);
    *(u16x4*)&Xb[i] = o;
  } else {
    const int bx = blockIdx.x - 2048;          // 768 blocks: 48 n x 16 k
    const int n0 = (bx % 48) * 32, k0 = (bx / 48) * 32;
    const int r = tid >> 3, c4 = (tid & 7) * 4;
    const float4 v = *(const float4*)&Wqkv[(size_t)(k0 + r) * 1536 + n0 + c4];
    t[r][c4 + 0] = v.x; t[r][c4 + 1] = v.y; t[r][c4 + 2] = v.z; t[r][c4 + 3] = v.w;
    __syncthreads();
    u16x4 o;
    o[0] = f2b(t[c4 + 0][r]);
    o[1] = f2b(t[c4 + 1][r]);
    o[2] = f2b(t[c4 + 2][r]);
    o[3] = f2b(t[c4 + 3][r]);
    *(u16x4*)&WqkvT[(n0 + r) * 512 + k0 + c4] = o;
  }
}

// ---------------------------------------------------------------------------
// Standalone W transpose (used post-attn for WoT).
// ---------------------------------------------------------------------------
__global__ __launch_bounds__(256)
void wtrans_kernel(const float* __restrict__ in, u16* __restrict__ out, int N)
{
  __shared__ float t[32][33];
  const int tid = threadIdx.x;
  const int r = tid >> 3, c4 = (tid & 7) * 4;
  const int k0 = blockIdx.y * 32, n0 = blockIdx.x * 32;
  const float4 v = *(const float4*)&in[(size_t)(k0 + r) * N + n0 + c4];
  t[r][c4 + 0] = v.x; t[r][c4 + 1] = v.y; t[r][c4 + 2] = v.z; t[r][c4 + 3] = v.w;
  __syncthreads();
  u16x4 o;
  o[0] = f2b(t[c4 + 0][r]);
  o[1] = f2b(t[c4 + 1][r]);
  o[2] = f2b(t[c4 + 2][r]);
  o[3] = f2b(t[c4 + 3][r]);
  *(u16x4*)&out[(n0 + r) * 512 + k0 + c4] = o;
}

// ---------------------------------------------------------------------------
// Unified bf16 GEMM (UNCHANGED — control).
// ---------------------------------------------------------------------------
template <int MODE>
__global__ __launch_bounds__(256, 2)
void gemm_kernel(const u16* __restrict__ A, const u16* __restrict__ Bt,
                 const float* __restrict__ bias,
                 u16* __restrict__ Q, u16* __restrict__ K, u16* __restrict__ Vt,
                 float* __restrict__ Out)
{
  __shared__ __align__(16) u16 As[128 * 40];
  __shared__ __align__(16) u16 Bs[128 * 40];
  const int tid  = threadIdx.x;
  const int lane = tid & 63, wave = tid >> 6, quad = lane >> 4, l16 = lane & 15;
  const int m0 = blockIdx.y * 128, n0 = blockIdx.x * 128;
  const int wr = (wave >> 1) * 64, wc = (wave & 1) * 64;
  const int sr = tid >> 2, sc = (tid & 3) * 8;

  const f32x4 z4 = {0.f, 0.f, 0.f, 0.f};
  f32x4 acc[4][4];
#pragma unroll
  for (int i = 0; i < 4; i++)
#pragma unroll
    for (int j = 0; j < 4; j++) acc[i][j] = z4;

  for (int k0 = 0; k0 < 512; k0 += 32) {
    const u16x8 a0 = *(const u16x8*)&A[(m0 + sr) * 512 + k0 + sc];
    const u16x8 a1 = *(const u16x8*)&A[(m0 + 64 + sr) * 512 + k0 + sc];
    const u16x8 b0 = *(const u16x8*)&Bt[(n0 + sr) * 512 + k0 + sc];
    const u16x8 b1 = *(const u16x8*)&Bt[(n0 + 64 + sr) * 512 + k0 + sc];
    __syncthreads();
    *(u16x8*)&As[sr * 40 + sc]        = a0;
    *(u16x8*)&As[(64 + sr) * 40 + sc] = a1;
    *(u16x8*)&Bs[sr * 40 + sc]        = b0;
    *(u16x8*)&Bs[(64 + sr) * 40 + sc] = b1;
    __syncthreads();
    bf16x8 af[4], bf[4];
#pragma unroll
    for (int i = 0; i < 4; i++) {
      af[i] = as_bf16x8(*(const u16x8*)&As[(wr + i * 16 + l16) * 40 + quad * 8]);
      bf[i] = as_bf16x8(*(const u16x8*)&Bs[(wc + i * 16 + l16) * 40 + quad * 8]);
    }
#pragma unroll
    for (int i = 0; i < 4; i++)
#pragma unroll
      for (int j = 0; j < 4; j++) acc[i][j] = MFMA16(af[i], bf[j], acc[i][j]);
  }

#pragma unroll
  for (int tm = 0; tm < 4; tm++) {
#pragma unroll
    for (int tn = 0; tn < 4; tn++) {
#pragma unroll
      for (int r = 0; r < 4; r++) {
        const int gm = m0 + wr + tm * 16 + quad * 4 + r;
        const int gn = n0 + wc + tn * 16 + l16;
        const float v = acc[tm][tn][r] + bias[gn];
        if (MODE == 0) {
          const int bb = gm >> 11, s = gm & 2047;
          const int hh = gn / 192, j = gn - hh * 192;
          const int bh = bb * SH + hh;
          if (j < 64)
            Q[(bh * SS + s) * SHD + j] = f2b(v * 0.125f);
          else if (j < 128)
            K[(bh * SS + s) * SHD + (j - 64)] = f2b(v);
          else
            Vt[(bh * SHD + (j - 128)) * SS + s] = f2b(v);
        } else {
          Out[gm * 512 + gn] = v;
        }
      }
    }
  }
}

// ---------------------------------------------------------------------------
// Fused attention v7 = v6 body + XCD-aware block swizzle.
// 1-D grid of 2048 blocks; wg = (bid&7)*256 + bid>>3 (bijective, 2048%8==0).
// XCD i (dispatch round-robin on bid%8) owns wg in [256i, 256i+256) =
// bh {2i, 2i+1} ONLY -> per-XCD K/V working set 1 MB <= 4 MB L2. The 1.07 GB
// of K/V re-reads move from Infinity Cache (~O(10) TB/s shared) to per-XCD
// L2 (~34.5 TB/s aggregate). Kernel body byte-identical to round 7.
// ---------------------------------------------------------------------------
#define PSTR 264
#define PWAVE (16 * PSTR)   // u16 elems per wave region (8448 B)
#define OSTR 72             // f32 stride for O-partial staging (16B aligned)

__global__ __launch_bounds__(512, 4)
void attn_kernel(const u16* __restrict__ Q, const u16* __restrict__ K,
                 const u16* __restrict__ Vt, u16* __restrict__ values,
                 float* __restrict__ attn)
{
  __shared__ __align__(16) u16 p_lds[8 * PWAVE];  // 67,584 B
  __shared__ float srm[8][16];
  __shared__ float srl[8][16];

  const int tid  = threadIdx.x;
  const int lane = tid & 63, wave = tid >> 6, quad = lane >> 4, l16 = lane & 15;

  // XCD swizzle: each XCD gets 2 (b,h) pairs x all 128 q-tiles
  const int bid = blockIdx.x;
  const int wg  = (bid & 7) * 256 + (bid >> 3);
  const int qt  = wg & 127;        // q-tile (16 rows)
  const int bh  = wg >> 7;         // 0..15
  const int h = bh & 7, b = bh >> 3;
  const int q0 = qt * 16;

  const u16* Qb = Q + (size_t)bh * SS * SHD;
  const u16* Kb = K + (size_t)bh * SS * SHD;
  const u16* Vb = Vt + (size_t)bh * SHD * SS;

  // Q fragments (B-operand; lane layout same as A)
  const bf16x8 aq0 = as_bf16x8(*(const u16x8*)&Qb[(q0 + l16) * SHD + quad * 8]);
  const bf16x8 aq1 = as_bf16x8(*(const u16x8*)&Qb[(q0 + l16) * SHD + 32 + quad * 8]);

  // ---- scores: acc[ct][r] = S[q = l16][key = ct*16 + quad*4 + r] ----
  f32x4 acc[16];
#pragma unroll
  for (int ct = 0; ct < 16; ct++) {
    const int kb = wave * 256 + ct * 16;
    bf16x8 bk0 = as_bf16x8(*(const u16x8*)&Kb[(kb + l16) * SHD + quad * 8]);
    bf16x8 bk1 = as_bf16x8(*(const u16x8*)&Kb[(kb + l16) * SHD + 32 + quad * 8]);
    f32x4 c = {0.f, 0.f, 0.f, 0.f};
    c = MFMA16(bk0, aq0, c);   // SWAPPED: A=K, B=Q
    c = MFMA16(bk1, aq1, c);
    acc[ct] = c;
  }

  // ---- per-lane stats for row q=l16 (64 in-reg values) ----
  f32x4 mx4 = acc[0];
#pragma unroll
  for (int ct = 1; ct < 16; ct++)
#pragma unroll
    for (int r = 0; r < 4; r++) mx4[r] = fmaxf(mx4[r], acc[ct][r]);
  float m = fmaxf(fmaxf(mx4[0], mx4[1]), fmaxf(mx4[2], mx4[3]));
  m = fmaxf(m, __shfl_xor(m, 16));
  m = fmaxf(m, __shfl_xor(m, 32));

  f32x4 s4 = {0.f, 0.f, 0.f, 0.f};
#pragma unroll
  for (int ct = 0; ct < 16; ct++)
#pragma unroll
    for (int r = 0; r < 4; r++) {
      const float p = __expf(acc[ct][r] - m);
      acc[ct][r] = p;
      s4[r] += p;
    }
  float s = (s4[0] + s4[1]) + (s4[2] + s4[3]);
  s += __shfl_xor(s, 16);
  s += __shfl_xor(s, 32);

  if (lane < 16) {   // quad == 0
    srm[wave][l16] = m;
    srl[wave][l16] = s;
  }
  __syncthreads();  // barrier #1

  // ---- global merge: scale = exp(m_w - m_g) / l_g ----
  float mg = srm[0][l16];
#pragma unroll
  for (int w = 1; w < 8; w++) mg = fmaxf(mg, srm[w][l16]);
  float lg = 0.f;
#pragma unroll
  for (int w = 0; w < 8; w++) lg += srl[w][l16] * __expf(srm[w][l16] - mg);
  const float scale = __expf(m - mg) / lg;
#pragma unroll
  for (int ct = 0; ct < 16; ct++)
#pragma unroll
    for (int r = 0; r < 4; r++) acc[ct][r] *= scale;

  // ---- bf16 P -> wave-private LDS ([q][key], 16x ds_write_b64) ----
  u16* pl = &p_lds[wave * PWAVE];
#pragma unroll
  for (int ct = 0; ct < 16; ct++) {
    u16x4 t;
#pragma unroll
    for (int r = 0; r < 4; r++) t[r] = f2b(acc[ct][r]);
    *(u16x4*)&pl[l16 * PSTR + ct * 16 + quad * 4] = t;
  }

  // ---- PV (swapped: A=V, B=P) with 2-deep V prefetch ----
  f32x4 oacc[4];
#pragma unroll
  for (int nt = 0; nt < 4; nt++) oacc[nt] = (f32x4){0.f, 0.f, 0.f, 0.f};
  bf16x8 vbuf[2][4];
  {
    const int sb = wave * 256 + quad * 8;
#pragma unroll
    for (int nt = 0; nt < 4; nt++)
      vbuf[0][nt] = as_bf16x8(*(const u16x8*)&Vb[(nt * 16 + l16) * SS + sb]);
  }
#pragma unroll
  for (int kc = 0; kc < 8; kc++) {
    if (kc < 7) {
      const int sb = wave * 256 + (kc + 1) * 32 + quad * 8;
#pragma unroll
      for (int nt = 0; nt < 4; nt++)
        vbuf[(kc + 1) & 1][nt] =
            as_bf16x8(*(const u16x8*)&Vb[(nt * 16 + l16) * SS + sb]);
    }
    bf16x8 pa = as_bf16x8(*(const u16x8*)&pl[l16 * PSTR + kc * 32 + quad * 8]);
#pragma unroll
    for (int nt = 0; nt < 4; nt++)
      oacc[nt] = MFMA16(vbuf[kc & 1][nt], pa, oacc[nt]);  // O[q=l16][d]
  }

  // ---- O partials [q][d] into own LDS region (4x ds_write_b128) ----
  float* op = (float*)pl;  // 16*OSTR*4 = 4608 B of 8448 B region
#pragma unroll
  for (int nt = 0; nt < 4; nt++)
    *(f32x4*)&op[l16 * OSTR + nt * 16 + quad * 4] = oacc[nt];
  __syncthreads();  // barrier #2

  // ---- cross-wave reduce + values write ----
  const int q = tid >> 5, d0 = (tid & 31) * 2;
  f32x2 s2 = {0.f, 0.f};
#pragma unroll
  for (int w = 0; w < 8; w++) {
    const float* opw = (const float*)&p_lds[w * PWAVE];
    s2 += *(const f32x2*)&opw[q * OSTR + d0];
  }
  u16x2 o2;
  o2[0] = f2b(s2[0]);
  o2[1] = f2b(s2[1]);
  *(u16x2*)&values[((size_t)(b * SS + q0 + q) * SH + h) * SHD + d0] = o2;

  // ---- LAST: NT fp32 P stores, 16x f32x4 (fire-and-forget) ----
  float* attn_b = attn + ((size_t)bh * SS + q0) * SS;
#pragma unroll
  for (int ct = 0; ct < 16; ct++) {
    __builtin_nontemporal_store(
        acc[ct],
        (f32x4*)&attn_b[l16 * SS + wave * 256 + ct * 16 + quad * 4]);
  }
}

// ---------------------------------------------------------------------------
// Workspace budget: EXACTLY 16 MiB (verified footprint).
//   ws: Q(4MB) K(4MB) Vt(4MB) values(4MB; Xb aliases it)
//   WqkvT: staged in d_out's attn region (dead until attn_kernel overwrites).
//   WoT:   aliases Q region; produced AFTER attn (Q dead), read by oproj.
// ---------------------------------------------------------------------------
extern "C" void kernel_launch(void* const* d_in, const int* in_sizes, int n_in,
                              void* d_out, int out_size, void* d_ws, size_t ws_size,
                              hipStream_t stream) {
  const float* X    = (const float*)d_in[0];
  const float* Wqkv = (const float*)d_in[1];
  const float* bqkv = (const float*)d_in[2];
  const float* Wo   = (const float*)d_in[3];
  const float* bo   = (const float*)d_in[4];

  float* o_out    = (float*)d_out;                       // [2,2048,512]
  float* attn_out = o_out + SB * SS * SE;                // [2,8,2048,2048]

  const size_t QKV_ELEMS = (size_t)SB * SH * SS * SHD;   // 2,097,152 per tensor
  u16* Q      = (u16*)d_ws;
  u16* K      = Q + QKV_ELEMS;
  u16* Vt     = K + QKV_ELEMS;
  u16* values = Vt + QKV_ELEMS;
  u16* Xb     = values;               // dead before attn writes values
  u16* WqkvT  = (u16*)attn_out;       // dead until attn writes attn_out
  u16* WoT    = Q;                    // Q dead after attn; WoT made post-attn

  // Merged prep: X conversion + Wqkv transpose (one launch)
  prep_kernel<<<dim3(2816), 256, 0, stream>>>(X, Xb, Wqkv, WqkvT);

  // QKV projection: M=4096 (32 m-blocks), N=1536 (12 n-blocks)
  gemm_kernel<0><<<dim3(12, 32), 256, 0, stream>>>(Xb, WqkvT, bqkv, Q, K, Vt, nullptr);
  // Attention: 2048 blocks, XCD-swizzled (2 bh per XCD -> K/V L2-resident)
  attn_kernel<<<dim3(2048), 512, 0, stream>>>(Q, K, Vt, values, attn_out);
  // Wo transpose into (now-dead) Q region, then O projection
  wtrans_kernel<<<dim3(16, 16), 256, 0, stream>>>(Wo, WoT, 512);
  gemm_kernel<1><<<dim3(4, 32), 256, 0, stream>>>(values, WoT, bo,
                                                  nullptr, nullptr, nullptr, o_out);
}

// Round 9
// 423.371 us; speedup vs baseline: 1.0318x; 1.0211x over previous
//
#include <hip/hip_runtime.h>

typedef unsigned short u16;
typedef u16 u16x2 __attribute__((ext_vector_type(2)));
typedef u16 u16x4 __attribute__((ext_vector_type(4)));
typedef u16 u16x8 __attribute__((ext_vector_type(8)));
typedef __bf16 bf16x8 __attribute__((ext_vector_type(8)));
typedef float f32x4 __attribute__((ext_vector_type(4)));
typedef float f32x2 __attribute__((ext_vector_type(2)));

#define MFMA16(A, B, C) __builtin_amdgcn_mfma_f32_16x16x32_bf16(A, B, C, 0, 0, 0)

// Constants: B=2, S=2048, E=512, H=8, HD=64
#define SB 2
#define SS 2048
#define SE 512
#define SH 8
#define SHD 64

// Hardware RNE f32->bf16.
__device__ __forceinline__ u16 f2b(float f) {
  return __builtin_bit_cast(u16, (__bf16)f);
}

__device__ __forceinline__ bf16x8 as_bf16x8(u16x8 v) {
  return __builtin_bit_cast(bf16x8, v);
}

// ---------------------------------------------------------------------------
// Merged prep: blocks [0,2048) convert X f32->bf16; blocks [2048,2816)
// transpose+convert Wqkv into WqkvT [1536,512] bf16.
// ---------------------------------------------------------------------------
__global__ __launch_bounds__(256)
void prep_kernel(const float* __restrict__ X, u16* __restrict__ Xb,
                 const float* __restrict__ Wqkv, u16* __restrict__ WqkvT)
{
  __shared__ float t[32][33];
  const int tid = threadIdx.x;
  if (blockIdx.x < 2048) {
    const int i = (blockIdx.x * 256 + tid) * 4;
    const float4 v = *(const float4*)&X[i];
    u16x4 o;
    o[0] = f2b(v.x); o[1] = f2b(v.y); o[2] = f2b(v.z); o[3] = f2b(v.w);
    *(u16x4*)&Xb[i] = o;
  } else {
    const int bx = blockIdx.x - 2048;          // 768 blocks: 48 n x 16 k
    const int n0 = (bx % 48) * 32, k0 = (bx / 48) * 32;
    const int r = tid >> 3, c4 = (tid & 7) * 4;
    const float4 v = *(const float4*)&Wqkv[(size_t)(k0 + r) * 1536 + n0 + c4];
    t[r][c4 + 0] = v.x; t[r][c4 + 1] = v.y; t[r][c4 + 2] = v.z; t[r][c4 + 3] = v.w;
    __syncthreads();
    u16x4 o;
    o[0] = f2b(t[c4 + 0][r]);
    o[1] = f2b(t[c4 + 1][r]);
    o[2] = f2b(t[c4 + 2][r]);
    o[3] = f2b(t[c4 + 3][r]);
    *(u16x4*)&WqkvT[(n0 + r) * 512 + k0 + c4] = o;
  }
}

// ---------------------------------------------------------------------------
// Standalone W transpose (used post-attn for WoT).
// ---------------------------------------------------------------------------
__global__ __launch_bounds__(256)
void wtrans_kernel(const float* __restrict__ in, u16* __restrict__ out, int N)
{
  __shared__ float t[32][33];
  const int tid = threadIdx.x;
  const int r = tid >> 3, c4 = (tid & 7) * 4;
  const int k0 = blockIdx.y * 32, n0 = blockIdx.x * 32;
  const float4 v = *(const float4*)&in[(size_t)(k0 + r) * N + n0 + c4];
  t[r][c4 + 0] = v.x; t[r][c4 + 1] = v.y; t[r][c4 + 2] = v.z; t[r][c4 + 3] = v.w;
  __syncthreads();
  u16x4 o;
  o[0] = f2b(t[c4 + 0][r]);
  o[1] = f2b(t[c4 + 1][r]);
  o[2] = f2b(t[c4 + 2][r]);
  o[3] = f2b(t[c4 + 3][r]);
  *(u16x4*)&out[(n0 + r) * 512 + k0 + c4] = o;
}

// ---------------------------------------------------------------------------
// Unified bf16 GEMM (UNCHANGED — control).
// ---------------------------------------------------------------------------
template <int MODE>
__global__ __launch_bounds__(256, 2)
void gemm_kernel(const u16* __restrict__ A, const u16* __restrict__ Bt,
                 const float* __restrict__ bias,
                 u16* __restrict__ Q, u16* __restrict__ K, u16* __restrict__ Vt,
                 float* __restrict__ Out)
{
  __shared__ __align__(16) u16 As[128 * 40];
  __shared__ __align__(16) u16 Bs[128 * 40];
  const int tid  = threadIdx.x;
  const int lane = tid & 63, wave = tid >> 6, quad = lane >> 4, l16 = lane & 15;
  const int m0 = blockIdx.y * 128, n0 = blockIdx.x * 128;
  const int wr = (wave >> 1) * 64, wc = (wave & 1) * 64;
  const int sr = tid >> 2, sc = (tid & 3) * 8;

  const f32x4 z4 = {0.f, 0.f, 0.f, 0.f};
  f32x4 acc[4][4];
#pragma unroll
  for (int i = 0; i < 4; i++)
#pragma unroll
    for (int j = 0; j < 4; j++) acc[i][j] = z4;

  for (int k0 = 0; k0 < 512; k0 += 32) {
    const u16x8 a0 = *(const u16x8*)&A[(m0 + sr) * 512 + k0 + sc];
    const u16x8 a1 = *(const u16x8*)&A[(m0 + 64 + sr) * 512 + k0 + sc];
    const u16x8 b0 = *(const u16x8*)&Bt[(n0 + sr) * 512 + k0 + sc];
    const u16x8 b1 = *(const u16x8*)&Bt[(n0 + 64 + sr) * 512 + k0 + sc];
    __syncthreads();
    *(u16x8*)&As[sr * 40 + sc]        = a0;
    *(u16x8*)&As[(64 + sr) * 40 + sc] = a1;
    *(u16x8*)&Bs[sr * 40 + sc]        = b0;
    *(u16x8*)&Bs[(64 + sr) * 40 + sc] = b1;
    __syncthreads();
    bf16x8 af[4], bf[4];
#pragma unroll
    for (int i = 0; i < 4; i++) {
      af[i] = as_bf16x8(*(const u16x8*)&As[(wr + i * 16 + l16) * 40 + quad * 8]);
      bf[i] = as_bf16x8(*(const u16x8*)&Bs[(wc + i * 16 + l16) * 40 + quad * 8]);
    }
#pragma unroll
    for (int i = 0; i < 4; i++)
#pragma unroll
      for (int j = 0; j < 4; j++) acc[i][j] = MFMA16(af[i], bf[j], acc[i][j]);
  }

#pragma unroll
  for (int tm = 0; tm < 4; tm++) {
#pragma unroll
    for (int tn = 0; tn < 4; tn++) {
#pragma unroll
      for (int r = 0; r < 4; r++) {
        const int gm = m0 + wr + tm * 16 + quad * 4 + r;
        const int gn = n0 + wc + tn * 16 + l16;
        const float v = acc[tm][tn][r] + bias[gn];
        if (MODE == 0) {
          const int bb = gm >> 11, s = gm & 2047;
          const int hh = gn / 192, j = gn - hh * 192;
          const int bh = bb * SH + hh;
          if (j < 64)
            Q[(bh * SS + s) * SHD + j] = f2b(v * 0.125f);
          else if (j < 128)
            K[(bh * SS + s) * SHD + (j - 64)] = f2b(v);
          else
            Vt[(bh * SHD + (j - 128)) * SS + s] = f2b(v);
        } else {
          Out[gm * 512 + gn] = v;
        }
      }
    }
  }
}

// ---------------------------------------------------------------------------
// Fused attention v8 = v7 with REGULAR (cached) P stores instead of
// nontemporal. Theory: NT bypasses L2 write-allocate, so the 16-row x 64 B
// per-instruction store pattern reaches HBM as scattered 64 B partials
// (~25% write efficiency -> 1.6 TB/s observed, 266 MB = ~166 us). Regular
// stores let L2 merge the interleaved 64 B pieces (each row's full 1 KB is
// covered across the ct loop) into full-line writebacks. Round 8 proved the
// K/V read path is insensitive to L2 pollution (XCD swizzle null), so the
// NT hint protects nothing. Everything else byte-identical to round 8.
// ---------------------------------------------------------------------------
#define PSTR 264
#define PWAVE (16 * PSTR)   // u16 elems per wave region (8448 B)
#define OSTR 72             // f32 stride for O-partial staging (16B aligned)

__global__ __launch_bounds__(512, 4)
void attn_kernel(const u16* __restrict__ Q, const u16* __restrict__ K,
                 const u16* __restrict__ Vt, u16* __restrict__ values,
                 float* __restrict__ attn)
{
  __shared__ __align__(16) u16 p_lds[8 * PWAVE];  // 67,584 B
  __shared__ float srm[8][16];
  __shared__ float srl[8][16];

  const int tid  = threadIdx.x;
  const int lane = tid & 63, wave = tid >> 6, quad = lane >> 4, l16 = lane & 15;

  // XCD swizzle: each XCD gets 2 (b,h) pairs x all 128 q-tiles
  const int bid = blockIdx.x;
  const int wg  = (bid & 7) * 256 + (bid >> 3);
  const int qt  = wg & 127;        // q-tile (16 rows)
  const int bh  = wg >> 7;         // 0..15
  const int h = bh & 7, b = bh >> 3;
  const int q0 = qt * 16;

  const u16* Qb = Q + (size_t)bh * SS * SHD;
  const u16* Kb = K + (size_t)bh * SS * SHD;
  const u16* Vb = Vt + (size_t)bh * SHD * SS;

  // Q fragments (B-operand; lane layout same as A)
  const bf16x8 aq0 = as_bf16x8(*(const u16x8*)&Qb[(q0 + l16) * SHD + quad * 8]);
  const bf16x8 aq1 = as_bf16x8(*(const u16x8*)&Qb[(q0 + l16) * SHD + 32 + quad * 8]);

  // ---- scores: acc[ct][r] = S[q = l16][key = ct*16 + quad*4 + r] ----
  f32x4 acc[16];
#pragma unroll
  for (int ct = 0; ct < 16; ct++) {
    const int kb = wave * 256 + ct * 16;
    bf16x8 bk0 = as_bf16x8(*(const u16x8*)&Kb[(kb + l16) * SHD + quad * 8]);
    bf16x8 bk1 = as_bf16x8(*(const u16x8*)&Kb[(kb + l16) * SHD + 32 + quad * 8]);
    f32x4 c = {0.f, 0.f, 0.f, 0.f};
    c = MFMA16(bk0, aq0, c);   // SWAPPED: A=K, B=Q
    c = MFMA16(bk1, aq1, c);
    acc[ct] = c;
  }

  // ---- per-lane stats for row q=l16 (64 in-reg values) ----
  f32x4 mx4 = acc[0];
#pragma unroll
  for (int ct = 1; ct < 16; ct++)
#pragma unroll
    for (int r = 0; r < 4; r++) mx4[r] = fmaxf(mx4[r], acc[ct][r]);
  float m = fmaxf(fmaxf(mx4[0], mx4[1]), fmaxf(mx4[2], mx4[3]));
  m = fmaxf(m, __shfl_xor(m, 16));
  m = fmaxf(m, __shfl_xor(m, 32));

  f32x4 s4 = {0.f, 0.f, 0.f, 0.f};
#pragma unroll
  for (int ct = 0; ct < 16; ct++)
#pragma unroll
    for (int r = 0; r < 4; r++) {
      const float p = __expf(acc[ct][r] - m);
      acc[ct][r] = p;
      s4[r] += p;
    }
  float s = (s4[0] + s4[1]) + (s4[2] + s4[3]);
  s += __shfl_xor(s, 16);
  s += __shfl_xor(s, 32);

  if (lane < 16) {   // quad == 0
    srm[wave][l16] = m;
    srl[wave][l16] = s;
  }
  __syncthreads();  // barrier #1

  // ---- global merge: scale = exp(m_w - m_g) / l_g ----
  float mg = srm[0][l16];
#pragma unroll
  for (int w = 1; w < 8; w++) mg = fmaxf(mg, srm[w][l16]);
  float lg = 0.f;
#pragma unroll
  for (int w = 0; w < 8; w++) lg += srl[w][l16] * __expf(srm[w][l16] - mg);
  const float scale = __expf(m - mg) / lg;
#pragma unroll
  for (int ct = 0; ct < 16; ct++)
#pragma unroll
    for (int r = 0; r < 4; r++) acc[ct][r] *= scale;

  // ---- bf16 P -> wave-private LDS ([q][key], 16x ds_write_b64) ----
  u16* pl = &p_lds[wave * PWAVE];
#pragma unroll
  for (int ct = 0; ct < 16; ct++) {
    u16x4 t;
#pragma unroll
    for (int r = 0; r < 4; r++) t[r] = f2b(acc[ct][r]);
    *(u16x4*)&pl[l16 * PSTR + ct * 16 + quad * 4] = t;
  }

  // ---- PV (swapped: A=V, B=P) with 2-deep V prefetch ----
  f32x4 oacc[4];
#pragma unroll
  for (int nt = 0; nt < 4; nt++) oacc[nt] = (f32x4){0.f, 0.f, 0.f, 0.f};
  bf16x8 vbuf[2][4];
  {
    const int sb = wave * 256 + quad * 8;
#pragma unroll
    for (int nt = 0; nt < 4; nt++)
      vbuf[0][nt] = as_bf16x8(*(const u16x8*)&Vb[(nt * 16 + l16) * SS + sb]);
  }
#pragma unroll
  for (int kc = 0; kc < 8; kc++) {
    if (kc < 7) {
      const int sb = wave * 256 + (kc + 1) * 32 + quad * 8;
#pragma unroll
      for (int nt = 0; nt < 4; nt++)
        vbuf[(kc + 1) & 1][nt] =
            as_bf16x8(*(const u16x8*)&Vb[(nt * 16 + l16) * SS + sb]);
    }
    bf16x8 pa = as_bf16x8(*(const u16x8*)&pl[l16 * PSTR + kc * 32 + quad * 8]);
#pragma unroll
    for (int nt = 0; nt < 4; nt++)
      oacc[nt] = MFMA16(vbuf[kc & 1][nt], pa, oacc[nt]);  // O[q=l16][d]
  }

  // ---- O partials [q][d] into own LDS region (4x ds_write_b128) ----
  float* op = (float*)pl;  // 16*OSTR*4 = 4608 B of 8448 B region
#pragma unroll
  for (int nt = 0; nt < 4; nt++)
    *(f32x4*)&op[l16 * OSTR + nt * 16 + quad * 4] = oacc[nt];
  __syncthreads();  // barrier #2

  // ---- cross-wave reduce + values write ----
  const int q = tid >> 5, d0 = (tid & 31) * 2;
  f32x2 s2 = {0.f, 0.f};
#pragma unroll
  for (int w = 0; w < 8; w++) {
    const float* opw = (const float*)&p_lds[w * PWAVE];
    s2 += *(const f32x2*)&opw[q * OSTR + d0];
  }
  u16x2 o2;
  o2[0] = f2b(s2[0]);
  o2[1] = f2b(s2[1]);
  *(u16x2*)&values[((size_t)(b * SS + q0 + q) * SH + h) * SHD + d0] = o2;

  // ---- LAST: fp32 P stores through the cache (L2 write-allocate merges the
  //      interleaved 64 B pieces into full lines; was nontemporal) ----
  float* attn_b = attn + ((size_t)bh * SS + q0) * SS;
#pragma unroll
  for (int ct = 0; ct < 16; ct++) {
    *(f32x4*)&attn_b[l16 * SS + wave * 256 + ct * 16 + quad * 4] = acc[ct];
  }
}

// ---------------------------------------------------------------------------
// Workspace budget: EXACTLY 16 MiB (verified footprint).
//   ws: Q(4MB) K(4MB) Vt(4MB) values(4MB; Xb aliases it)
//   WqkvT: staged in d_out's attn region (dead until attn_kernel overwrites).
//   WoT:   aliases Q region; produced AFTER attn (Q dead), read by oproj.
// ---------------------------------------------------------------------------
extern "C" void kernel_launch(void* const* d_in, const int* in_sizes, int n_in,
                              void* d_out, int out_size, void* d_ws, size_t ws_size,
                              hipStream_t stream) {
  const float* X    = (const float*)d_in[0];
  const float* Wqkv = (const float*)d_in[1];
  const float* bqkv = (const float*)d_in[2];
  const float* Wo   = (const float*)d_in[3];
  const float* bo   = (const float*)d_in[4];

  float* o_out    = (float*)d_out;                       // [2,2048,512]
  float* attn_out = o_out + SB * SS * SE;                // [2,8,2048,2048]

  const size_t QKV_ELEMS = (size_t)SB * SH * SS * SHD;   // 2,097,152 per tensor
  u16* Q      = (u16*)d_ws;
  u16* K      = Q + QKV_ELEMS;
  u16* Vt     = K + QKV_ELEMS;
  u16* values = Vt + QKV_ELEMS;
  u16* Xb     = values;               // dead before attn writes values
  u16* WqkvT  = (u16*)attn_out;       // dead until attn writes attn_out
  u16* WoT    = Q;                    // Q dead after attn; WoT made post-attn

  // Merged prep: X conversion + Wqkv transpose (one launch)
  prep_kernel<<<dim3(2816), 256, 0, stream>>>(X, Xb, Wqkv, WqkvT);

  // QKV projection: M=4096 (32 m-blocks), N=1536 (12 n-blocks)
  gemm_kernel<0><<<dim3(12, 32), 256, 0, stream>>>(Xb, WqkvT, bqkv, Q, K, Vt, nullptr);
  // Attention: 2048 blocks, XCD-swizzled
  attn_kernel<<<dim3(2048), 512, 0, stream>>>(Q, K, Vt, values, attn_out);
  // Wo transpose into (now-dead) Q region, then O projection
  wtrans_kernel<<<dim3(16, 16), 256, 0, stream>>>(Wo, WoT, 512);
  gemm_kernel<1><<<dim3(4, 32), 256, 0, stream>>>(values, WoT, bo,
                                                  nullptr, nullptr, nullptr, o_out);
}

// Round 10
// 416.750 us; speedup vs baseline: 1.0481x; 1.0159x over previous
//
#include <hip/hip_runtime.h>

typedef unsigned short u16;
typedef u16 u16x2 __attribute__((ext_vector_type(2)));
typedef u16 u16x4 __attribute__((ext_vector_type(4)));
typedef u16 u16x8 __attribute__((ext_vector_type(8)));
typedef __bf16 bf16x8 __attribute__((ext_vector_type(8)));
typedef float f32x4 __attribute__((ext_vector_type(4)));
typedef float f32x2 __attribute__((ext_vector_type(2)));

#define MFMA16(A, B, C) __builtin_amdgcn_mfma_f32_16x16x32_bf16(A, B, C, 0, 0, 0)

// Constants: B=2, S=2048, E=512, H=8, HD=64
#define SB 2
#define SS 2048
#define SE 512
#define SH 8
#define SHD 64

// Hardware RNE f32->bf16.
__device__ __forceinline__ u16 f2b(float f) {
  return __builtin_bit_cast(u16, (__bf16)f);
}

__device__ __forceinline__ bf16x8 as_bf16x8(u16x8 v) {
  return __builtin_bit_cast(bf16x8, v);
}

// ---------------------------------------------------------------------------
// Merged prep: blocks [0,2048) convert X f32->bf16; blocks [2048,2816)
// transpose+convert Wqkv into WqkvT [1536,512] bf16.
// ---------------------------------------------------------------------------
__global__ __launch_bounds__(256)
void prep_kernel(const float* __restrict__ X, u16* __restrict__ Xb,
                 const float* __restrict__ Wqkv, u16* __restrict__ WqkvT)
{
  __shared__ float t[32][33];
  const int tid = threadIdx.x;
  if (blockIdx.x < 2048) {
    const int i = (blockIdx.x * 256 + tid) * 4;
    const float4 v = *(const float4*)&X[i];
    u16x4 o;
    o[0] = f2b(v.x); o[1] = f2b(v.y); o[2] = f2b(v.z); o[3] = f2b(v.w);
    *(u16x4*)&Xb[i] = o;
  } else {
    const int bx = blockIdx.x - 2048;          // 768 blocks: 48 n x 16 k
    const int n0 = (bx % 48) * 32, k0 = (bx / 48) * 32;
    const int r = tid >> 3, c4 = (tid & 7) * 4;
    const float4 v = *(const float4*)&Wqkv[(size_t)(k0 + r) * 1536 + n0 + c4];
    t[r][c4 + 0] = v.x; t[r][c4 + 1] = v.y; t[r][c4 + 2] = v.z; t[r][c4 + 3] = v.w;
    __syncthreads();
    u16x4 o;
    o[0] = f2b(t[c4 + 0][r]);
    o[1] = f2b(t[c4 + 1][r]);
    o[2] = f2b(t[c4 + 2][r]);
    o[3] = f2b(t[c4 + 3][r]);
    *(u16x4*)&WqkvT[(n0 + r) * 512 + k0 + c4] = o;
  }
}

// ---------------------------------------------------------------------------
// Standalone W transpose (used post-attn for WoT).
// ---------------------------------------------------------------------------
__global__ __launch_bounds__(256)
void wtrans_kernel(const float* __restrict__ in, u16* __restrict__ out, int N)
{
  __shared__ float t[32][33];
  const int tid = threadIdx.x;
  const int r = tid >> 3, c4 = (tid & 7) * 4;
  const int k0 = blockIdx.y * 32, n0 = blockIdx.x * 32;
  const float4 v = *(const float4*)&in[(size_t)(k0 + r) * N + n0 + c4];
  t[r][c4 + 0] = v.x; t[r][c4 + 1] = v.y; t[r][c4 + 2] = v.z; t[r][c4 + 3] = v.w;
  __syncthreads();
  u16x4 o;
  o[0] = f2b(t[c4 + 0][r]);
  o[1] = f2b(t[c4 + 1][r]);
  o[2] = f2b(t[c4 + 2][r]);
  o[3] = f2b(t[c4 + 3][r]);
  *(u16x4*)&out[(n0 + r) * 512 + k0 + c4] = o;
}

// ---------------------------------------------------------------------------
// Unified bf16 GEMM (UNCHANGED — control).
// ---------------------------------------------------------------------------
template <int MODE>
__global__ __launch_bounds__(256, 2)
void gemm_kernel(const u16* __restrict__ A, const u16* __restrict__ Bt,
                 const float* __restrict__ bias,
                 u16* __restrict__ Q, u16* __restrict__ K, u16* __restrict__ Vt,
                 float* __restrict__ Out)
{
  __shared__ __align__(16) u16 As[128 * 40];
  __shared__ __align__(16) u16 Bs[128 * 40];
  const int tid  = threadIdx.x;
  const int lane = tid & 63, wave = tid >> 6, quad = lane >> 4, l16 = lane & 15;
  const int m0 = blockIdx.y * 128, n0 = blockIdx.x * 128;
  const int wr = (wave >> 1) * 64, wc = (wave & 1) * 64;
  const int sr = tid >> 2, sc = (tid & 3) * 8;

  const f32x4 z4 = {0.f, 0.f, 0.f, 0.f};
  f32x4 acc[4][4];
#pragma unroll
  for (int i = 0; i < 4; i++)
#pragma unroll
    for (int j = 0; j < 4; j++) acc[i][j] = z4;

  for (int k0 = 0; k0 < 512; k0 += 32) {
    const u16x8 a0 = *(const u16x8*)&A[(m0 + sr) * 512 + k0 + sc];
    const u16x8 a1 = *(const u16x8*)&A[(m0 + 64 + sr) * 512 + k0 + sc];
    const u16x8 b0 = *(const u16x8*)&Bt[(n0 + sr) * 512 + k0 + sc];
    const u16x8 b1 = *(const u16x8*)&Bt[(n0 + 64 + sr) * 512 + k0 + sc];
    __syncthreads();
    *(u16x8*)&As[sr * 40 + sc]        = a0;
    *(u16x8*)&As[(64 + sr) * 40 + sc] = a1;
    *(u16x8*)&Bs[sr * 40 + sc]        = b0;
    *(u16x8*)&Bs[(64 + sr) * 40 + sc] = b1;
    __syncthreads();
    bf16x8 af[4], bf[4];
#pragma unroll
    for (int i = 0; i < 4; i++) {
      af[i] = as_bf16x8(*(const u16x8*)&As[(wr + i * 16 + l16) * 40 + quad * 8]);
      bf[i] = as_bf16x8(*(const u16x8*)&Bs[(wc + i * 16 + l16) * 40 + quad * 8]);
    }
#pragma unroll
    for (int i = 0; i < 4; i++)
#pragma unroll
      for (int j = 0; j < 4; j++) acc[i][j] = MFMA16(af[i], bf[j], acc[i][j]);
  }

#pragma unroll
  for (int tm = 0; tm < 4; tm++) {
#pragma unroll
    for (int tn = 0; tn < 4; tn++) {
#pragma unroll
      for (int r = 0; r < 4; r++) {
        const int gm = m0 + wr + tm * 16 + quad * 4 + r;
        const int gn = n0 + wc + tn * 16 + l16;
        const float v = acc[tm][tn][r] + bias[gn];
        if (MODE == 0) {
          const int bb = gm >> 11, s = gm & 2047;
          const int hh = gn / 192, j = gn - hh * 192;
          const int bh = bb * SH + hh;
          if (j < 64)
            Q[(bh * SS + s) * SHD + j] = f2b(v * 0.125f);
          else if (j < 128)
            K[(bh * SS + s) * SHD + (j - 64)] = f2b(v);
          else
            Vt[(bh * SHD + (j - 128)) * SS + s] = f2b(v);
        } else {
          Out[gm * 512 + gn] = v;
        }
      }
    }
  }
}

// ---------------------------------------------------------------------------
// Fused attention v9 = v8 + LDS-bounced CONTIGUOUS fp32 P stores.
// Theory: the old P store wrote, per instruction, 16 segments of 64 B at an
// exact 8192 B stride. Channel hashing uses address bits ~[12:8], which an
// 8 KB stride leaves invariant -> all 16 segments hit ONE channel and
// serialize (~1.6 TB/s observed vs 6.3 on contiguous fill; NT-vs-cached and
// XCD swizzle both null because neither changes the ADDRESS pattern).
// Fix: after the O reduce, each wave round-trips its 16 KB fp32 P chunk
// through its (dead) LDS region in two 8-row passes, then stores each row
// chunk as ONE 1 KB-contiguous instruction (64 lanes x 16 B) — the fill
// kernel's own pattern. XOR swizzle keeps both LDS phases ~conflict-free.
// Pure store reorder: output bits identical.
// ---------------------------------------------------------------------------
#define PSTR 264
#define PWAVE (16 * PSTR)   // u16 elems per wave region (8448 B)
#define OSTR 72             // f32 stride for O-partial staging (16B aligned)

__global__ __launch_bounds__(512, 4)
void attn_kernel(const u16* __restrict__ Q, const u16* __restrict__ K,
                 const u16* __restrict__ Vt, u16* __restrict__ values,
                 float* __restrict__ attn)
{
  __shared__ __align__(16) u16 p_lds[8 * PWAVE];  // 67,584 B
  __shared__ float srm[8][16];
  __shared__ float srl[8][16];

  const int tid  = threadIdx.x;
  const int lane = tid & 63, wave = tid >> 6, quad = lane >> 4, l16 = lane & 15;

  // XCD swizzle: each XCD gets 2 (b,h) pairs x all 128 q-tiles
  const int bid = blockIdx.x;
  const int wg  = (bid & 7) * 256 + (bid >> 3);
  const int qt  = wg & 127;        // q-tile (16 rows)
  const int bh  = wg >> 7;         // 0..15
  const int h = bh & 7, b = bh >> 3;
  const int q0 = qt * 16;

  const u16* Qb = Q + (size_t)bh * SS * SHD;
  const u16* Kb = K + (size_t)bh * SS * SHD;
  const u16* Vb = Vt + (size_t)bh * SHD * SS;

  // Q fragments (B-operand; lane layout same as A)
  const bf16x8 aq0 = as_bf16x8(*(const u16x8*)&Qb[(q0 + l16) * SHD + quad * 8]);
  const bf16x8 aq1 = as_bf16x8(*(const u16x8*)&Qb[(q0 + l16) * SHD + 32 + quad * 8]);

  // ---- scores: acc[ct][r] = S[q = l16][key = ct*16 + quad*4 + r] ----
  f32x4 acc[16];
#pragma unroll
  for (int ct = 0; ct < 16; ct++) {
    const int kb = wave * 256 + ct * 16;
    bf16x8 bk0 = as_bf16x8(*(const u16x8*)&Kb[(kb + l16) * SHD + quad * 8]);
    bf16x8 bk1 = as_bf16x8(*(const u16x8*)&Kb[(kb + l16) * SHD + 32 + quad * 8]);
    f32x4 c = {0.f, 0.f, 0.f, 0.f};
    c = MFMA16(bk0, aq0, c);   // SWAPPED: A=K, B=Q
    c = MFMA16(bk1, aq1, c);
    acc[ct] = c;
  }

  // ---- per-lane stats for row q=l16 (64 in-reg values) ----
  f32x4 mx4 = acc[0];
#pragma unroll
  for (int ct = 1; ct < 16; ct++)
#pragma unroll
    for (int r = 0; r < 4; r++) mx4[r] = fmaxf(mx4[r], acc[ct][r]);
  float m = fmaxf(fmaxf(mx4[0], mx4[1]), fmaxf(mx4[2], mx4[3]));
  m = fmaxf(m, __shfl_xor(m, 16));
  m = fmaxf(m, __shfl_xor(m, 32));

  f32x4 s4 = {0.f, 0.f, 0.f, 0.f};
#pragma unroll
  for (int ct = 0; ct < 16; ct++)
#pragma unroll
    for (int r = 0; r < 4; r++) {
      const float p = __expf(acc[ct][r] - m);
      acc[ct][r] = p;
      s4[r] += p;
    }
  float s = (s4[0] + s4[1]) + (s4[2] + s4[3]);
  s += __shfl_xor(s, 16);
  s += __shfl_xor(s, 32);

  if (lane < 16) {   // quad == 0
    srm[wave][l16] = m;
    srl[wave][l16] = s;
  }
  __syncthreads();  // barrier #1

  // ---- global merge: scale = exp(m_w - m_g) / l_g ----
  float mg = srm[0][l16];
#pragma unroll
  for (int w = 1; w < 8; w++) mg = fmaxf(mg, srm[w][l16]);
  float lg = 0.f;
#pragma unroll
  for (int w = 0; w < 8; w++) lg += srl[w][l16] * __expf(srm[w][l16] - mg);
  const float scale = __expf(m - mg) / lg;
#pragma unroll
  for (int ct = 0; ct < 16; ct++)
#pragma unroll
    for (int r = 0; r < 4; r++) acc[ct][r] *= scale;

  // ---- bf16 P -> wave-private LDS ([q][key], 16x ds_write_b64) ----
  u16* pl = &p_lds[wave * PWAVE];
#pragma unroll
  for (int ct = 0; ct < 16; ct++) {
    u16x4 t;
#pragma unroll
    for (int r = 0; r < 4; r++) t[r] = f2b(acc[ct][r]);
    *(u16x4*)&pl[l16 * PSTR + ct * 16 + quad * 4] = t;
  }

  // ---- PV (swapped: A=V, B=P) with 2-deep V prefetch ----
  f32x4 oacc[4];
#pragma unroll
  for (int nt = 0; nt < 4; nt++) oacc[nt] = (f32x4){0.f, 0.f, 0.f, 0.f};
  bf16x8 vbuf[2][4];
  {
    const int sb = wave * 256 + quad * 8;
#pragma unroll
    for (int nt = 0; nt < 4; nt++)
      vbuf[0][nt] = as_bf16x8(*(const u16x8*)&Vb[(nt * 16 + l16) * SS + sb]);
  }
#pragma unroll
  for (int kc = 0; kc < 8; kc++) {
    if (kc < 7) {
      const int sb = wave * 256 + (kc + 1) * 32 + quad * 8;
#pragma unroll
      for (int nt = 0; nt < 4; nt++)
        vbuf[(kc + 1) & 1][nt] =
            as_bf16x8(*(const u16x8*)&Vb[(nt * 16 + l16) * SS + sb]);
    }
    bf16x8 pa = as_bf16x8(*(const u16x8*)&pl[l16 * PSTR + kc * 32 + quad * 8]);
#pragma unroll
    for (int nt = 0; nt < 4; nt++)
      oacc[nt] = MFMA16(vbuf[kc & 1][nt], pa, oacc[nt]);  // O[q=l16][d]
  }

  // ---- O partials [q][d] into own LDS region (4x ds_write_b128) ----
  float* op = (float*)pl;  // 16*OSTR*4 = 4608 B of 8448 B region
#pragma unroll
  for (int nt = 0; nt < 4; nt++)
    *(f32x4*)&op[l16 * OSTR + nt * 16 + quad * 4] = oacc[nt];
  __syncthreads();  // barrier #2

  // ---- cross-wave reduce + values write ----
  const int q = tid >> 5, d0 = (tid & 31) * 2;
  f32x2 s2 = {0.f, 0.f};
#pragma unroll
  for (int w = 0; w < 8; w++) {
    const float* opw = (const float*)&p_lds[w * PWAVE];
    s2 += *(const f32x2*)&opw[q * OSTR + d0];
  }
  u16x2 o2;
  o2[0] = f2b(s2[0]);
  o2[1] = f2b(s2[1]);
  *(u16x2*)&values[((size_t)(b * SS + q0 + q) * SH + h) * SHD + d0] = o2;

  __syncthreads();  // barrier #3: all waves done reading op regions

  // ---- LAST: fp32 P via LDS bounce -> 1 KB-contiguous row-chunk stores ----
  // Two passes of 8 rows. Holder lanes (l16 in [8c,8c+8)) deposit their row's
  // 64 floats; then all 64 lanes re-read row-major and emit one contiguous
  // 1 KB store per row (64 lanes x 16 B). XOR swizzle (colf ^ row) spreads
  // LDS banks on the divergent write phase. Bounce uses 8192 B of the wave's
  // 8448 B region (op data dead after barrier #3).
  float* bb2 = (float*)pl;
  float* attn_b = attn + ((size_t)bh * SS + q0) * SS;
#pragma unroll
  for (int c = 0; c < 2; c++) {
    if ((l16 >> 3) == c) {
      const int row = l16 & 7;
#pragma unroll
      for (int ct = 0; ct < 16; ct++) {
        const int colf = ct * 4 + quad;                  // 16B block in [0,64)
        *(f32x4*)&bb2[row * 256 + ((colf ^ row) * 4)] = acc[ct];
      }
    }
    asm volatile("s_waitcnt lgkmcnt(0)" ::: "memory");
#pragma unroll
    for (int rr = 0; rr < 8; rr++) {
      const f32x4 v = *(const f32x4*)&bb2[rr * 256 + ((lane ^ rr) * 4)];
      *(f32x4*)&attn_b[(size_t)(c * 8 + rr) * SS + wave * 256 + lane * 4] = v;
    }
    // per-wave in-order DS guarantees pass-2 writes can't pass pass-1 reads
  }
}

// ---------------------------------------------------------------------------
// Workspace budget: EXACTLY 16 MiB (verified footprint).
//   ws: Q(4MB) K(4MB) Vt(4MB) values(4MB; Xb aliases it)
//   WqkvT: staged in d_out's attn region (dead until attn_kernel overwrites).
//   WoT:   aliases Q region; produced AFTER attn (Q dead), read by oproj.
// ---------------------------------------------------------------------------
extern "C" void kernel_launch(void* const* d_in, const int* in_sizes, int n_in,
                              void* d_out, int out_size, void* d_ws, size_t ws_size,
                              hipStream_t stream) {
  const float* X    = (const float*)d_in[0];
  const float* Wqkv = (const float*)d_in[1];
  const float* bqkv = (const float*)d_in[2];
  const float* Wo   = (const float*)d_in[3];
  const float* bo   = (const float*)d_in[4];

  float* o_out    = (float*)d_out;                       // [2,2048,512]
  float* attn_out = o_out + SB * SS * SE;                // [2,8,2048,2048]

  const size_t QKV_ELEMS = (size_t)SB * SH * SS * SHD;   // 2,097,152 per tensor
  u16* Q      = (u16*)d_ws;
  u16* K      = Q + QKV_ELEMS;
  u16* Vt     = K + QKV_ELEMS;
  u16* values = Vt + QKV_ELEMS;
  u16* Xb     = values;               // dead before attn writes values
  u16* WqkvT  = (u16*)attn_out;       // dead until attn writes attn_out
  u16* WoT    = Q;                    // Q dead after attn; WoT made post-attn

  // Merged prep: X conversion + Wqkv transpose (one launch)
  prep_kernel<<<dim3(2816), 256, 0, stream>>>(X, Xb, Wqkv, WqkvT);

  // QKV projection: M=4096 (32 m-blocks), N=1536 (12 n-blocks)
  gemm_kernel<0><<<dim3(12, 32), 256, 0, stream>>>(Xb, WqkvT, bqkv, Q, K, Vt, nullptr);
  // Attention: 2048 blocks, XCD-swizzled
  attn_kernel<<<dim3(2048), 512, 0, stream>>>(Q, K, Vt, values, attn_out);
  // Wo transpose into (now-dead) Q region, then O projection
  wtrans_kernel<<<dim3(16, 16), 256, 0, stream>>>(Wo, WoT, 512);
  gemm_kernel<1><<<dim3(4, 32), 256, 0, stream>>>(values, WoT, bo,
                                                  nullptr, nullptr, nullptr, o_out);
}